// Round 1
// baseline (835.612 us; speedup 1.0000x reference)
//
#include <hip/hip_runtime.h>

#define FEAT 128

// ---------------------------------------------------------------------------
// CSR build: histogram -> exclusive scan -> scatter (recomputed every call;
// ws is re-poisoned before every timed launch so nothing may persist).
// ---------------------------------------------------------------------------

__global__ void hist_kernel(const int* __restrict__ dst, int* __restrict__ deg, int E) {
    int e = blockIdx.x * blockDim.x + threadIdx.x;
    if (e < E) atomicAdd(&deg[dst[e]], 1);
}

__global__ __launch_bounds__(1024) void scan_kernel(const int* __restrict__ deg,
                                                    int* __restrict__ row_ptr,
                                                    int N, int E) {
    __shared__ int part[1024];
    int tid = threadIdx.x;
    int C = (N + 1023) >> 10;
    int start = tid * C;
    int end = start + C;
    if (start > N) start = N;
    if (end > N) end = N;
    int s = 0;
    for (int i = start; i < end; ++i) s += deg[i];
    part[tid] = s;
    __syncthreads();
    // Hillis-Steele inclusive scan over 1024 partials
    for (int off = 1; off < 1024; off <<= 1) {
        int mine = part[tid];
        int other = (tid >= off) ? part[tid - off] : 0;
        __syncthreads();
        part[tid] = mine + other;
        __syncthreads();
    }
    int run = (tid > 0) ? part[tid - 1] : 0;  // exclusive prefix for this chunk
    for (int i = start; i < end; ++i) { row_ptr[i] = run; run += deg[i]; }
    if (tid == 1023) row_ptr[N] = E;
}

__global__ void scatter_kernel(const int* __restrict__ src, const int* __restrict__ dst,
                               const int* __restrict__ row_ptr, int* __restrict__ fill,
                               int* __restrict__ esrc, int E) {
    int e = blockIdx.x * blockDim.x + threadIdx.x;
    if (e < E) {
        int d = dst[e];
        int pos = row_ptr[d] + atomicAdd(&fill[d], 1);
        esrc[pos] = src[e];  // order within a segment irrelevant for max
    }
}

// ---------------------------------------------------------------------------
// GEMM: Out[m][j] = sum_k X[m][k] * W[j][k]   (torch Linear: x @ W.T)
// M=50000, K=128, one weight matrix (theta or phi) per blockIdx.y.
// Tile 128x128, 256 threads, 8x8 micro-tile, float4 LDS reads.
// Column/row interleave (c = tcol + 16*ic) keeps LDS bank conflicts <=2-way.
// ---------------------------------------------------------------------------

__global__ __launch_bounds__(256) void gemm_kernel(
        const float* __restrict__ X,
        const float* __restrict__ TW, const float* __restrict__ PW,
        float* __restrict__ Tout, float* __restrict__ Pout, int M) {
    const float* W = (blockIdx.y == 0) ? TW : PW;
    float* Out = (blockIdx.y == 0) ? Tout : Pout;

    __shared__ __align__(16) float xs[128][20];  // +4 pad: float4-aligned, banks ok
    __shared__ __align__(16) float ws[128][20];

    int tid = threadIdx.x;
    int tcol = tid & 15;
    int trow = tid >> 4;
    int mbase = blockIdx.x * 128;

    float acc[8][8];
#pragma unroll
    for (int i = 0; i < 8; ++i)
#pragma unroll
        for (int j = 0; j < 8; ++j) acc[i][j] = 0.0f;

    for (int kc = 0; kc < FEAT; kc += 16) {
#pragma unroll
        for (int i = 0; i < 2; ++i) {
            int l = tid + i * 256;       // 0..511
            int r = l >> 2;              // 0..127
            int k4 = (l & 3) * 4;        // 0,4,8,12
            int grow = mbase + r;
            float4 xv = make_float4(0.f, 0.f, 0.f, 0.f);
            if (grow < M) xv = *(const float4*)(X + (size_t)grow * FEAT + kc + k4);
            *(float4*)&xs[r][k4] = xv;
            float4 wv = *(const float4*)(W + (size_t)r * FEAT + kc + k4);
            *(float4*)&ws[r][k4] = wv;
        }
        __syncthreads();
#pragma unroll
        for (int kk = 0; kk < 16; kk += 4) {
            float4 xf[8], wf[8];
#pragma unroll
            for (int ir = 0; ir < 8; ++ir) xf[ir] = *(const float4*)&xs[trow + 16 * ir][kk];
#pragma unroll
            for (int ic = 0; ic < 8; ++ic) wf[ic] = *(const float4*)&ws[tcol + 16 * ic][kk];
#pragma unroll
            for (int ir = 0; ir < 8; ++ir)
#pragma unroll
                for (int ic = 0; ic < 8; ++ic) {
                    acc[ir][ic] += xf[ir].x * wf[ic].x + xf[ir].y * wf[ic].y +
                                   xf[ir].z * wf[ic].z + xf[ir].w * wf[ic].w;
                }
        }
        __syncthreads();
    }

#pragma unroll
    for (int ir = 0; ir < 8; ++ir) {
        int row = mbase + trow + 16 * ir;
        if (row < M) {
#pragma unroll
            for (int ic = 0; ic < 8; ++ic)
                Out[(size_t)row * FEAT + tcol + 16 * ic] = acc[ir][ic];
        }
    }
}

// ---------------------------------------------------------------------------
// Aggregation + epilogue: one wave per node, lane holds 2 features (float2).
// out[i][f] = deg>0 ? max( max_{e->i} t[src_e][f] - t[i][f] + tb[f] + pb[f] + p[i][f], 0 ) : 0
// (segment_max -inf -> where->0 -> relu  collapses to exactly this.)
// ---------------------------------------------------------------------------

__global__ __launch_bounds__(256) void agg_kernel(
        const float* __restrict__ t, const float* __restrict__ p,
        const float* __restrict__ tb, const float* __restrict__ pb,
        const int* __restrict__ row_ptr, const int* __restrict__ esrc,
        float* __restrict__ out, int N) {
    int wv = threadIdx.x >> 6;
    int lane = threadIdx.x & 63;
    int node = blockIdx.x * 4 + wv;
    if (node >= N) return;

    int beg = row_ptr[node];
    int end = row_ptr[node + 1];

    const float2* t2 = (const float2*)t;
    float2 m = make_float2(-__builtin_inff(), -__builtin_inff());

    int e = beg;
    for (; e + 1 < end; e += 2) {   // 2-way unroll: two independent load chains
        int s0 = esrc[e];
        int s1 = esrc[e + 1];
        float2 v0 = t2[(size_t)s0 * 64 + lane];
        float2 v1 = t2[(size_t)s1 * 64 + lane];
        m.x = fmaxf(m.x, fmaxf(v0.x, v1.x));
        m.y = fmaxf(m.y, fmaxf(v0.y, v1.y));
    }
    if (e < end) {
        int s0 = esrc[e];
        float2 v0 = t2[(size_t)s0 * 64 + lane];
        m.x = fmaxf(m.x, v0.x);
        m.y = fmaxf(m.y, v0.y);
    }

    float2 ti = t2[(size_t)node * 64 + lane];
    float2 pi = ((const float2*)p)[(size_t)node * 64 + lane];
    float2 tbv = ((const float2*)tb)[lane];
    float2 pbv = ((const float2*)pb)[lane];

    float2 o = make_float2(0.f, 0.f);
    if (beg < end) {
        o.x = fmaxf(m.x - ti.x + tbv.x + pbv.x + pi.x, 0.f);
        o.y = fmaxf(m.y - ti.y + tbv.y + pbv.y + pi.y, 0.f);
    }
    ((float2*)out)[(size_t)node * 64 + lane] = o;
}

// ---------------------------------------------------------------------------

extern "C" void kernel_launch(void* const* d_in, const int* in_sizes, int n_in,
                              void* d_out, int out_size, void* d_ws, size_t ws_size,
                              hipStream_t stream) {
    const float* feats   = (const float*)d_in[0];
    const int*   src     = (const int*)d_in[1];
    const int*   dst     = (const int*)d_in[2];
    const float* theta_w = (const float*)d_in[3];
    const float* theta_b = (const float*)d_in[4];
    const float* phi_w   = (const float*)d_in[5];
    const float* phi_b   = (const float*)d_in[6];

    const int N = in_sizes[0] / FEAT;
    const int E = in_sizes[1];
    const int L = in_sizes[3] / (FEAT * FEAT);

    char* ws = (char*)d_ws;
    size_t off = 0;
    auto alloc = [&](size_t bytes) -> void* {
        void* ptr = ws + off;
        off = (off + bytes + 255) & ~(size_t)255;
        return ptr;
    };
    float* tbuf    = (float*)alloc((size_t)N * FEAT * sizeof(float));
    float* pbuf    = (float*)alloc((size_t)N * FEAT * sizeof(float));
    float* xA      = (float*)alloc((size_t)N * FEAT * sizeof(float));
    int*   deg     = (int*)alloc((size_t)N * sizeof(int));
    int*   fill    = (int*)alloc((size_t)N * sizeof(int));
    int*   row_ptr = (int*)alloc((size_t)(N + 1) * sizeof(int));
    int*   esrc    = (int*)alloc((size_t)E * sizeof(int));
    (void)ws_size;

    hipMemsetAsync(deg, 0, (size_t)N * sizeof(int), stream);
    hipMemsetAsync(fill, 0, (size_t)N * sizeof(int), stream);

    int eb = (E + 255) / 256;
    hist_kernel<<<eb, 256, 0, stream>>>(dst, deg, E);
    scan_kernel<<<1, 1024, 0, stream>>>(deg, row_ptr, N, E);
    scatter_kernel<<<eb, 256, 0, stream>>>(src, dst, row_ptr, fill, esrc, E);

    // Layer ping-pong: feats -> xA -> d_out -> xA -> d_out  (d_out doubles as
    // scratch for odd layers; fully overwritten by the final layer.)
    const float* xin = feats;
    for (int l = 0; l < L; ++l) {
        float* xout = (l & 1) ? (float*)d_out : xA;
        if (l == L - 1) xout = (float*)d_out;

        dim3 ggrid((N + 127) / 128, 2);
        gemm_kernel<<<ggrid, 256, 0, stream>>>(
            xin,
            theta_w + (size_t)l * FEAT * FEAT,
            phi_w + (size_t)l * FEAT * FEAT,
            tbuf, pbuf, N);

        agg_kernel<<<(N + 3) / 4, 256, 0, stream>>>(
            tbuf, pbuf,
            theta_b + (size_t)l * FEAT,
            phi_b + (size_t)l * FEAT,
            row_ptr, esrc, xout, N);

        xin = xout;
    }
}

// Round 2
// 606.035 us; speedup vs baseline: 1.3788x; 1.3788x over previous
//
#include <hip/hip_runtime.h>

#define FEAT 128

typedef __attribute__((ext_vector_type(8))) short bf16x8;
typedef __attribute__((ext_vector_type(4))) float f32x4;

static __device__ __forceinline__ unsigned short f2bf_rne(float f) {
    unsigned int u = __float_as_uint(f);
    unsigned int r = (u + 0x7fffu + ((u >> 16) & 1u)) >> 16;
    return (unsigned short)r;
}
static __device__ __forceinline__ float bf2f(unsigned short h) {
    return __uint_as_float(((unsigned int)h) << 16);
}

// ---------------------------------------------------------------------------
// CSR build: histogram -> single-block scan -> scatter (rebuilt every call).
// ---------------------------------------------------------------------------

__global__ void hist_kernel(const int* __restrict__ dst, int* __restrict__ deg, int E) {
    int e = blockIdx.x * blockDim.x + threadIdx.x;
    if (e < E) atomicAdd(&deg[dst[e]], 1);
}

__global__ __launch_bounds__(1024) void scan_kernel(const int* __restrict__ deg,
                                                    int* __restrict__ row_ptr,
                                                    int N, int E) {
    __shared__ int part[1024];
    int tid = threadIdx.x;
    int C = (N + 1023) >> 10;
    int start = tid * C, end = start + C;
    if (start > N) start = N;
    if (end > N) end = N;
    int s = 0;
    for (int i = start; i < end; ++i) s += deg[i];
    part[tid] = s;
    __syncthreads();
    for (int off = 1; off < 1024; off <<= 1) {
        int mine = part[tid];
        int other = (tid >= off) ? part[tid - off] : 0;
        __syncthreads();
        part[tid] = mine + other;
        __syncthreads();
    }
    int run = (tid > 0) ? part[tid - 1] : 0;
    for (int i = start; i < end; ++i) { row_ptr[i] = run; run += deg[i]; }
    if (tid == 1023) row_ptr[N] = E;
}

__global__ void scatter_kernel(const int* __restrict__ src, const int* __restrict__ dst,
                               const int* __restrict__ row_ptr, int* __restrict__ fill,
                               int* __restrict__ esrc, int E) {
    int e = blockIdx.x * blockDim.x + threadIdx.x;
    if (e < E) {
        int d = dst[e];
        int pos = row_ptr[d] + atomicAdd(&fill[d], 1);
        esrc[pos] = src[e];  // order within a segment irrelevant for max
    }
}

// ---------------------------------------------------------------------------
// Split fp32 -> bf16 hi + bf16 lo (residual). Covers both weight tensors.
// ---------------------------------------------------------------------------

__global__ void wsplit_kernel(const float* __restrict__ tw, const float* __restrict__ pw,
                              unsigned short* __restrict__ th, unsigned short* __restrict__ tl,
                              unsigned short* __restrict__ ph, unsigned short* __restrict__ pl,
                              int n) {
    int i = blockIdx.x * blockDim.x + threadIdx.x;
    if (i >= n) return;
    float a = tw[i];
    unsigned short h = f2bf_rne(a);
    th[i] = h; tl[i] = f2bf_rne(a - bf2f(h));
    float b = pw[i];
    h = f2bf_rne(b);
    ph[i] = h; pl[i] = f2bf_rne(b - bf2f(h));
}

__global__ void xsplit_kernel(const float* __restrict__ x,
                              unsigned short* __restrict__ xh, unsigned short* __restrict__ xl,
                              int n) {
    int i = blockIdx.x * blockDim.x + threadIdx.x;
    if (i >= n) return;
    float a = x[i];
    unsigned short h = f2bf_rne(a);
    xh[i] = h; xl[i] = f2bf_rne(a - bf2f(h));
}

// ---------------------------------------------------------------------------
// MFMA GEMM: Out[m][j] = sum_k x[m][k] * W[j][k]  via split-bf16:
//   x ~ xh + xl, W ~ wh + wl;  x*W ~ xh*wh + xh*wl + xl*wh  (~fp32 accurate)
// Block = 4 waves; wave owns 32 cols (B frags live in regs for whole block);
// 128 rows/block in 8 steps of 16. No LDS, no barriers.
// blockIdx.y picks theta (0) or phi (1).
// A frag:  lane reads x[rbase+(lane&15)][kk*32+(lane>>4)*8 ..+7]  (16B).
// B frag:  lane reads W[cn+(lane&15)][kk*32+(lane>>4)*8 ..+7]     (16B).
// C/D:     col = lane&15, row = (lane>>4)*4 + reg.
// ---------------------------------------------------------------------------

__global__ __launch_bounds__(256) void mfma_gemm_kernel(
        const unsigned short* __restrict__ xh, const unsigned short* __restrict__ xl,
        const unsigned short* __restrict__ wh_t, const unsigned short* __restrict__ wl_t,
        const unsigned short* __restrict__ wh_p, const unsigned short* __restrict__ wl_p,
        float* __restrict__ Tout, float* __restrict__ Pout, int M) {
    const unsigned short* WH = (blockIdx.y == 0) ? wh_t : wh_p;
    const unsigned short* WL = (blockIdx.y == 0) ? wl_t : wl_p;
    float* Out = (blockIdx.y == 0) ? Tout : Pout;

    int wave = threadIdx.x >> 6;
    int lane = threadIdx.x & 63;
    int l16 = lane & 15;
    int quad = lane >> 4;
    int cn0 = wave * 32;

    bf16x8 bh[2][4], bl[2][4];
#pragma unroll
    for (int ct = 0; ct < 2; ++ct) {
        int col = cn0 + ct * 16 + l16;
#pragma unroll
        for (int kk = 0; kk < 4; ++kk) {
            int k = kk * 32 + quad * 8;
            bh[ct][kk] = *(const bf16x8*)(WH + (size_t)col * FEAT + k);
            bl[ct][kk] = *(const bf16x8*)(WL + (size_t)col * FEAT + k);
        }
    }

    int rbase0 = blockIdx.x * 128;
#pragma unroll 1
    for (int rs = 0; rs < 8; ++rs) {
        int rbase = rbase0 + rs * 16;
        int row = rbase + l16;
        int rowc = (row < M) ? row : (M - 1);
        bf16x8 ah[4], al[4];
#pragma unroll
        for (int kk = 0; kk < 4; ++kk) {
            int k = kk * 32 + quad * 8;
            ah[kk] = *(const bf16x8*)(xh + (size_t)rowc * FEAT + k);
            al[kk] = *(const bf16x8*)(xl + (size_t)rowc * FEAT + k);
        }
        f32x4 acc[2] = {{0.f, 0.f, 0.f, 0.f}, {0.f, 0.f, 0.f, 0.f}};
#pragma unroll
        for (int kk = 0; kk < 4; ++kk) {
#pragma unroll
            for (int ct = 0; ct < 2; ++ct) {
                acc[ct] = __builtin_amdgcn_mfma_f32_16x16x32_bf16(ah[kk], bh[ct][kk], acc[ct], 0, 0, 0);
                acc[ct] = __builtin_amdgcn_mfma_f32_16x16x32_bf16(ah[kk], bl[ct][kk], acc[ct], 0, 0, 0);
                acc[ct] = __builtin_amdgcn_mfma_f32_16x16x32_bf16(al[kk], bh[ct][kk], acc[ct], 0, 0, 0);
            }
        }
#pragma unroll
        for (int ct = 0; ct < 2; ++ct) {
            int col = cn0 + ct * 16 + l16;
#pragma unroll
            for (int r = 0; r < 4; ++r) {
                int ro = rbase + quad * 4 + r;
                if (ro < M) Out[(size_t)ro * FEAT + col] = acc[ct][r];
            }
        }
    }
}

// ---------------------------------------------------------------------------
// Aggregation + epilogue. One wave per node, lane holds 2 features.
// o = relu( max_e t[src_e] - t[i] + tb + pb + p[i] ), 0 for edgeless nodes.
// Writes next-layer bf16 split (xh/xl) and/or fp32 final output.
// ---------------------------------------------------------------------------

__global__ __launch_bounds__(256) void agg_kernel(
        const float* __restrict__ t, const float* __restrict__ p,
        const float* __restrict__ tb, const float* __restrict__ pb,
        const int* __restrict__ row_ptr, const int* __restrict__ esrc,
        float* __restrict__ outf,
        unsigned short* __restrict__ oxh, unsigned short* __restrict__ oxl,
        int N) {
    int wv = threadIdx.x >> 6;
    int lane = threadIdx.x & 63;
    int node = blockIdx.x * 4 + wv;
    if (node >= N) return;

    int beg = row_ptr[node];
    int end = row_ptr[node + 1];

    const float2* t2 = (const float2*)t;
    float2 m = make_float2(-__builtin_inff(), -__builtin_inff());

    int e = beg;
    for (; e + 1 < end; e += 2) {
        int s0 = esrc[e];
        int s1 = esrc[e + 1];
        float2 v0 = t2[(size_t)s0 * 64 + lane];
        float2 v1 = t2[(size_t)s1 * 64 + lane];
        m.x = fmaxf(m.x, fmaxf(v0.x, v1.x));
        m.y = fmaxf(m.y, fmaxf(v0.y, v1.y));
    }
    if (e < end) {
        int s0 = esrc[e];
        float2 v0 = t2[(size_t)s0 * 64 + lane];
        m.x = fmaxf(m.x, v0.x);
        m.y = fmaxf(m.y, v0.y);
    }

    float2 ti = t2[(size_t)node * 64 + lane];
    float2 pi = ((const float2*)p)[(size_t)node * 64 + lane];
    float2 tbv = ((const float2*)tb)[lane];
    float2 pbv = ((const float2*)pb)[lane];

    float2 o = make_float2(0.f, 0.f);
    if (beg < end) {
        o.x = fmaxf(m.x - ti.x + tbv.x + pbv.x + pi.x, 0.f);
        o.y = fmaxf(m.y - ti.y + tbv.y + pbv.y + pi.y, 0.f);
    }

    if (outf) {
        ((float2*)outf)[(size_t)node * 64 + lane] = o;
    }
    if (oxh) {
        unsigned short hx = f2bf_rne(o.x);
        unsigned short hy = f2bf_rne(o.y);
        unsigned short lx = f2bf_rne(o.x - bf2f(hx));
        unsigned short ly = f2bf_rne(o.y - bf2f(hy));
        ushort2 hv; hv.x = hx; hv.y = hy;
        ushort2 lv; lv.x = lx; lv.y = ly;
        ((ushort2*)oxh)[(size_t)node * 64 + lane] = hv;
        ((ushort2*)oxl)[(size_t)node * 64 + lane] = lv;
    }
}

// ---------------------------------------------------------------------------

extern "C" void kernel_launch(void* const* d_in, const int* in_sizes, int n_in,
                              void* d_out, int out_size, void* d_ws, size_t ws_size,
                              hipStream_t stream) {
    const float* feats   = (const float*)d_in[0];
    const int*   src     = (const int*)d_in[1];
    const int*   dst     = (const int*)d_in[2];
    const float* theta_w = (const float*)d_in[3];
    const float* theta_b = (const float*)d_in[4];
    const float* phi_w   = (const float*)d_in[5];
    const float* phi_b   = (const float*)d_in[6];

    const int N = in_sizes[0] / FEAT;
    const int E = in_sizes[1];
    const int L = in_sizes[3] / (FEAT * FEAT);

    char* ws = (char*)d_ws;
    size_t off = 0;
    auto alloc = [&](size_t bytes) -> void* {
        void* ptr = ws + off;
        off = (off + bytes + 255) & ~(size_t)255;
        return ptr;
    };
    float* tbuf = (float*)alloc((size_t)N * FEAT * sizeof(float));
    float* pbuf = (float*)alloc((size_t)N * FEAT * sizeof(float));
    unsigned short* xh = (unsigned short*)alloc((size_t)N * FEAT * 2);
    unsigned short* xl = (unsigned short*)alloc((size_t)N * FEAT * 2);
    unsigned short* wth = (unsigned short*)alloc((size_t)L * FEAT * FEAT * 2);
    unsigned short* wtl = (unsigned short*)alloc((size_t)L * FEAT * FEAT * 2);
    unsigned short* wph = (unsigned short*)alloc((size_t)L * FEAT * FEAT * 2);
    unsigned short* wpl = (unsigned short*)alloc((size_t)L * FEAT * FEAT * 2);
    int* deg     = (int*)alloc((size_t)N * sizeof(int));
    int* fill    = (int*)alloc((size_t)N * sizeof(int));
    int* row_ptr = (int*)alloc((size_t)(N + 1) * sizeof(int));
    int* esrc    = (int*)alloc((size_t)E * sizeof(int));
    (void)ws_size;

    hipMemsetAsync(deg, 0, (size_t)N * sizeof(int), stream);
    hipMemsetAsync(fill, 0, (size_t)N * sizeof(int), stream);

    int eb = (E + 255) / 256;
    hist_kernel<<<eb, 256, 0, stream>>>(dst, deg, E);
    scan_kernel<<<1, 1024, 0, stream>>>(deg, row_ptr, N, E);
    scatter_kernel<<<eb, 256, 0, stream>>>(src, dst, row_ptr, fill, esrc, E);

    int wn = L * FEAT * FEAT;
    wsplit_kernel<<<(wn + 255) / 256, 256, 0, stream>>>(theta_w, phi_w, wth, wtl, wph, wpl, wn);
    int xn = N * FEAT;
    xsplit_kernel<<<(xn + 255) / 256, 256, 0, stream>>>(feats, xh, xl, xn);

    dim3 ggrid((N + 127) / 128, 2);
    for (int l = 0; l < L; ++l) {
        mfma_gemm_kernel<<<ggrid, 256, 0, stream>>>(
            xh, xl,
            wth + (size_t)l * FEAT * FEAT, wtl + (size_t)l * FEAT * FEAT,
            wph + (size_t)l * FEAT * FEAT, wpl + (size_t)l * FEAT * FEAT,
            tbuf, pbuf, N);

        bool last = (l == L - 1);
        agg_kernel<<<(N + 3) / 4, 256, 0, stream>>>(
            tbuf, pbuf,
            theta_b + (size_t)l * FEAT,
            phi_b + (size_t)l * FEAT,
            row_ptr, esrc,
            last ? (float*)d_out : nullptr,
            last ? nullptr : xh,
            last ? nullptr : xl,
            N);
    }
}

// Round 3
// 502.403 us; speedup vs baseline: 1.6632x; 1.2063x over previous
//
#include <hip/hip_runtime.h>

#define FEAT 128

typedef __attribute__((ext_vector_type(8))) short bf16x8;
typedef __attribute__((ext_vector_type(4))) float f32x4;

static __device__ __forceinline__ unsigned short f2bf_rne(float f) {
    unsigned int u = __float_as_uint(f);
    unsigned int r = (u + 0x7fffu + ((u >> 16) & 1u)) >> 16;
    return (unsigned short)r;
}
static __device__ __forceinline__ float bf2f(unsigned short h) {
    return __uint_as_float(((unsigned int)h) << 16);
}

static __device__ __forceinline__ int wave_incl_scan(int v, int lane) {
#pragma unroll
    for (int off = 1; off < 64; off <<= 1) {
        int u = __shfl_up(v, off, 64);
        if (lane >= off) v += u;
    }
    return v;
}

// ---------------------------------------------------------------------------
// CSR build: histogram -> 3-phase parallel scan -> scatter.
// ---------------------------------------------------------------------------

__global__ void hist_kernel(const int* __restrict__ dst, int* __restrict__ deg, int E) {
    int e = blockIdx.x * blockDim.x + threadIdx.x;
    if (e < E) atomicAdd(&deg[dst[e]], 1);
}

// Phase 1: per-block (1024 elems) exclusive scan -> row_ptr, block total -> bsum.
__global__ __launch_bounds__(1024) void scan1_kernel(const int* __restrict__ deg,
                                                     int* __restrict__ row_ptr,
                                                     int* __restrict__ bsum, int N) {
    int i = blockIdx.x * 1024 + threadIdx.x;
    int lane = threadIdx.x & 63;
    int w = threadIdx.x >> 6;
    int v = (i < N) ? deg[i] : 0;
    int inc = wave_incl_scan(v, lane);
    __shared__ int wsum[16];
    if (lane == 63) wsum[w] = inc;
    __syncthreads();
    if (w == 0) {
        int s = (lane < 16) ? wsum[lane] : 0;
        int si = wave_incl_scan(s, lane);
        if (lane < 16) wsum[lane] = si - s;  // exclusive wave offsets
    }
    __syncthreads();
    int exc = inc - v + wsum[w];
    if (i < N) row_ptr[i] = exc;
    if (threadIdx.x == 1023) bsum[blockIdx.x] = exc + v;  // block total
}

// Phase 2: single block scans bsum[nb] -> boff (exclusive); writes row_ptr[N]=E.
__global__ __launch_bounds__(1024) void scan2_kernel(const int* __restrict__ bsum,
                                                     int* __restrict__ boff,
                                                     int* __restrict__ row_ptr,
                                                     int nb, int N, int E) {
    int tid = threadIdx.x;
    int lane = tid & 63;
    int w = tid >> 6;
    int v = (tid < nb) ? bsum[tid] : 0;
    int inc = wave_incl_scan(v, lane);
    __shared__ int wsum[16];
    if (lane == 63) wsum[w] = inc;
    __syncthreads();
    if (w == 0) {
        int s = (lane < 16) ? wsum[lane] : 0;
        int si = wave_incl_scan(s, lane);
        if (lane < 16) wsum[lane] = si - s;
    }
    __syncthreads();
    if (tid < nb) boff[tid] = inc - v + wsum[w];
    if (tid == 0) row_ptr[N] = E;
}

// Phase 3: add block offsets.
__global__ void scan3_kernel(int* __restrict__ row_ptr, const int* __restrict__ boff, int N) {
    int i = blockIdx.x * blockDim.x + threadIdx.x;
    if (i < N) row_ptr[i] += boff[i >> 10];
}

__global__ void scatter_kernel(const int* __restrict__ src, const int* __restrict__ dst,
                               const int* __restrict__ row_ptr, int* __restrict__ fill,
                               int* __restrict__ esrc, int E) {
    int e = blockIdx.x * blockDim.x + threadIdx.x;
    if (e < E) {
        int d = dst[e];
        int pos = row_ptr[d] + atomicAdd(&fill[d], 1);
        esrc[pos] = src[e];  // order within a segment irrelevant for max
    }
}

// ---------------------------------------------------------------------------
// Split fp32 -> bf16 hi + bf16 lo (residual).
// ---------------------------------------------------------------------------

__global__ void wsplit_kernel(const float* __restrict__ tw, const float* __restrict__ pw,
                              unsigned short* __restrict__ th, unsigned short* __restrict__ tl,
                              unsigned short* __restrict__ ph, unsigned short* __restrict__ pl,
                              int n) {
    int i = blockIdx.x * blockDim.x + threadIdx.x;
    if (i >= n) return;
    float a = tw[i];
    unsigned short h = f2bf_rne(a);
    th[i] = h; tl[i] = f2bf_rne(a - bf2f(h));
    float b = pw[i];
    h = f2bf_rne(b);
    ph[i] = h; pl[i] = f2bf_rne(b - bf2f(h));
}

__global__ void xsplit_kernel(const float* __restrict__ x,
                              unsigned short* __restrict__ xh, unsigned short* __restrict__ xl,
                              int n) {
    int i = blockIdx.x * blockDim.x + threadIdx.x;
    if (i >= n) return;
    float a = x[i];
    unsigned short h = f2bf_rne(a);
    xh[i] = h; xl[i] = f2bf_rne(a - bf2f(h));
}

// ---------------------------------------------------------------------------
// MFMA GEMM: Out[m][j] = sum_k x[m][k] * W[j][k]  via split-bf16 (3 products).
// Block = 4 waves; wave owns 32 cols; B frags in regs for whole block; no LDS.
// blockIdx.y: 0 = theta (bf16 output!), 1 = phi (fp32 output).
// C/D layout: col = lane&15, row = (lane>>4)*4 + reg.
// ---------------------------------------------------------------------------

__global__ __launch_bounds__(256) void mfma_gemm_kernel(
        const unsigned short* __restrict__ xh, const unsigned short* __restrict__ xl,
        const unsigned short* __restrict__ wh_t, const unsigned short* __restrict__ wl_t,
        const unsigned short* __restrict__ wh_p, const unsigned short* __restrict__ wl_p,
        unsigned short* __restrict__ Tb16, float* __restrict__ Pout, int M) {
    const unsigned short* WH = (blockIdx.y == 0) ? wh_t : wh_p;
    const unsigned short* WL = (blockIdx.y == 0) ? wl_t : wl_p;

    int wave = threadIdx.x >> 6;
    int lane = threadIdx.x & 63;
    int l16 = lane & 15;
    int quad = lane >> 4;
    int cn0 = wave * 32;

    bf16x8 bh[2][4], bl[2][4];
#pragma unroll
    for (int ct = 0; ct < 2; ++ct) {
        int col = cn0 + ct * 16 + l16;
#pragma unroll
        for (int kk = 0; kk < 4; ++kk) {
            int k = kk * 32 + quad * 8;
            bh[ct][kk] = *(const bf16x8*)(WH + (size_t)col * FEAT + k);
            bl[ct][kk] = *(const bf16x8*)(WL + (size_t)col * FEAT + k);
        }
    }

    int rbase0 = blockIdx.x * 128;
#pragma unroll 1
    for (int rs = 0; rs < 8; ++rs) {
        int rbase = rbase0 + rs * 16;
        int row = rbase + l16;
        int rowc = (row < M) ? row : (M - 1);
        bf16x8 ah[4], al[4];
#pragma unroll
        for (int kk = 0; kk < 4; ++kk) {
            int k = kk * 32 + quad * 8;
            ah[kk] = *(const bf16x8*)(xh + (size_t)rowc * FEAT + k);
            al[kk] = *(const bf16x8*)(xl + (size_t)rowc * FEAT + k);
        }
        f32x4 acc[2] = {{0.f, 0.f, 0.f, 0.f}, {0.f, 0.f, 0.f, 0.f}};
#pragma unroll
        for (int kk = 0; kk < 4; ++kk) {
#pragma unroll
            for (int ct = 0; ct < 2; ++ct) {
                acc[ct] = __builtin_amdgcn_mfma_f32_16x16x32_bf16(ah[kk], bh[ct][kk], acc[ct], 0, 0, 0);
                acc[ct] = __builtin_amdgcn_mfma_f32_16x16x32_bf16(ah[kk], bl[ct][kk], acc[ct], 0, 0, 0);
                acc[ct] = __builtin_amdgcn_mfma_f32_16x16x32_bf16(al[kk], bh[ct][kk], acc[ct], 0, 0, 0);
            }
        }
        if (blockIdx.y == 0) {
#pragma unroll
            for (int ct = 0; ct < 2; ++ct) {
                int col = cn0 + ct * 16 + l16;
#pragma unroll
                for (int r = 0; r < 4; ++r) {
                    int ro = rbase + quad * 4 + r;
                    if (ro < M) Tb16[(size_t)ro * FEAT + col] = f2bf_rne(acc[ct][r]);
                }
            }
        } else {
#pragma unroll
            for (int ct = 0; ct < 2; ++ct) {
                int col = cn0 + ct * 16 + l16;
#pragma unroll
                for (int r = 0; r < 4; ++r) {
                    int ro = rbase + quad * 4 + r;
                    if (ro < M) Pout[(size_t)ro * FEAT + col] = acc[ct][r];
                }
            }
        }
    }
}

// ---------------------------------------------------------------------------
// Aggregation + epilogue. One wave per node, lane holds 2 features.
// Gathers from bf16 t (max commutes with monotone RNE rounding).
// o = relu( max_e t[src_e] - t[i] + tb + pb + p[i] ), 0 for edgeless nodes.
// ---------------------------------------------------------------------------

__global__ __launch_bounds__(256) void agg_kernel(
        const unsigned short* __restrict__ tb16, const float* __restrict__ p,
        const float* __restrict__ tb, const float* __restrict__ pb,
        const int* __restrict__ row_ptr, const int* __restrict__ esrc,
        float* __restrict__ outf,
        unsigned short* __restrict__ oxh, unsigned short* __restrict__ oxl,
        int N) {
    int wv = threadIdx.x >> 6;
    int lane = threadIdx.x & 63;
    int node = blockIdx.x * 4 + wv;
    if (node >= N) return;

    int beg = row_ptr[node];
    int end = row_ptr[node + 1];

    const ushort2* t2 = (const ushort2*)tb16;  // row = 64 ushort2
    float2 m = make_float2(-__builtin_inff(), -__builtin_inff());

    int e = beg;
    for (; e + 1 < end; e += 2) {
        int s0 = esrc[e];
        int s1 = esrc[e + 1];
        ushort2 r0 = t2[(size_t)s0 * 64 + lane];
        ushort2 r1 = t2[(size_t)s1 * 64 + lane];
        m.x = fmaxf(m.x, fmaxf(bf2f(r0.x), bf2f(r1.x)));
        m.y = fmaxf(m.y, fmaxf(bf2f(r0.y), bf2f(r1.y)));
    }
    if (e < end) {
        ushort2 r0 = t2[(size_t)esrc[e] * 64 + lane];
        m.x = fmaxf(m.x, bf2f(r0.x));
        m.y = fmaxf(m.y, bf2f(r0.y));
    }

    ushort2 tir = t2[(size_t)node * 64 + lane];
    float2 pi = ((const float2*)p)[(size_t)node * 64 + lane];
    float2 tbv = ((const float2*)tb)[lane];
    float2 pbv = ((const float2*)pb)[lane];

    float2 o = make_float2(0.f, 0.f);
    if (beg < end) {
        o.x = fmaxf(m.x - bf2f(tir.x) + tbv.x + pbv.x + pi.x, 0.f);
        o.y = fmaxf(m.y - bf2f(tir.y) + tbv.y + pbv.y + pi.y, 0.f);
    }

    if (outf) {
        ((float2*)outf)[(size_t)node * 64 + lane] = o;
    }
    if (oxh) {
        unsigned short hx = f2bf_rne(o.x);
        unsigned short hy = f2bf_rne(o.y);
        unsigned short lx = f2bf_rne(o.x - bf2f(hx));
        unsigned short ly = f2bf_rne(o.y - bf2f(hy));
        ushort2 hv; hv.x = hx; hv.y = hy;
        ushort2 lv; lv.x = lx; lv.y = ly;
        ((ushort2*)oxh)[(size_t)node * 64 + lane] = hv;
        ((ushort2*)oxl)[(size_t)node * 64 + lane] = lv;
    }
}

// ---------------------------------------------------------------------------

extern "C" void kernel_launch(void* const* d_in, const int* in_sizes, int n_in,
                              void* d_out, int out_size, void* d_ws, size_t ws_size,
                              hipStream_t stream) {
    const float* feats   = (const float*)d_in[0];
    const int*   src     = (const int*)d_in[1];
    const int*   dst     = (const int*)d_in[2];
    const float* theta_w = (const float*)d_in[3];
    const float* theta_b = (const float*)d_in[4];
    const float* phi_w   = (const float*)d_in[5];
    const float* phi_b   = (const float*)d_in[6];

    const int N = in_sizes[0] / FEAT;
    const int E = in_sizes[1];
    const int L = in_sizes[3] / (FEAT * FEAT);

    char* ws = (char*)d_ws;
    size_t off = 0;
    auto alloc = [&](size_t bytes) -> void* {
        void* ptr = ws + off;
        off = (off + bytes + 255) & ~(size_t)255;
        return ptr;
    };
    unsigned short* tb16 = (unsigned short*)alloc((size_t)N * FEAT * 2);
    float* pbuf = (float*)alloc((size_t)N * FEAT * sizeof(float));
    unsigned short* xh = (unsigned short*)alloc((size_t)N * FEAT * 2);
    unsigned short* xl = (unsigned short*)alloc((size_t)N * FEAT * 2);
    unsigned short* wth = (unsigned short*)alloc((size_t)L * FEAT * FEAT * 2);
    unsigned short* wtl = (unsigned short*)alloc((size_t)L * FEAT * FEAT * 2);
    unsigned short* wph = (unsigned short*)alloc((size_t)L * FEAT * FEAT * 2);
    unsigned short* wpl = (unsigned short*)alloc((size_t)L * FEAT * FEAT * 2);
    int* deg     = (int*)alloc((size_t)N * sizeof(int));
    int* fill    = (int*)alloc((size_t)N * sizeof(int));
    int* row_ptr = (int*)alloc((size_t)(N + 1) * sizeof(int));
    int* esrc    = (int*)alloc((size_t)E * sizeof(int));
    int* bsum    = (int*)alloc(2048 * sizeof(int));
    int* boff    = (int*)alloc(2048 * sizeof(int));
    (void)ws_size;

    hipMemsetAsync(deg, 0, (size_t)N * sizeof(int), stream);
    hipMemsetAsync(fill, 0, (size_t)N * sizeof(int), stream);

    int eb = (E + 255) / 256;
    int nb = (N + 1023) >> 10;
    hist_kernel<<<eb, 256, 0, stream>>>(dst, deg, E);
    scan1_kernel<<<nb, 1024, 0, stream>>>(deg, row_ptr, bsum, N);
    scan2_kernel<<<1, 1024, 0, stream>>>(bsum, boff, row_ptr, nb, N, E);
    scan3_kernel<<<(N + 255) / 256, 256, 0, stream>>>(row_ptr, boff, N);
    scatter_kernel<<<eb, 256, 0, stream>>>(src, dst, row_ptr, fill, esrc, E);

    int wn = L * FEAT * FEAT;
    wsplit_kernel<<<(wn + 255) / 256, 256, 0, stream>>>(theta_w, phi_w, wth, wtl, wph, wpl, wn);
    int xn = N * FEAT;
    xsplit_kernel<<<(xn + 255) / 256, 256, 0, stream>>>(feats, xh, xl, xn);

    dim3 ggrid((N + 127) / 128, 2);
    for (int l = 0; l < L; ++l) {
        mfma_gemm_kernel<<<ggrid, 256, 0, stream>>>(
            xh, xl,
            wth + (size_t)l * FEAT * FEAT, wtl + (size_t)l * FEAT * FEAT,
            wph + (size_t)l * FEAT * FEAT, wpl + (size_t)l * FEAT * FEAT,
            tb16, pbuf, N);

        bool last = (l == L - 1);
        agg_kernel<<<(N + 3) / 4, 256, 0, stream>>>(
            tb16, pbuf,
            theta_b + (size_t)l * FEAT,
            phi_b + (size_t)l * FEAT,
            row_ptr, esrc,
            last ? (float*)d_out : nullptr,
            last ? nullptr : xh,
            last ? nullptr : xl,
            N);
    }
}

// Round 4
// 347.936 us; speedup vs baseline: 2.4016x; 1.4439x over previous
//
#include <hip/hip_runtime.h>

#define FEAT 128

typedef __attribute__((ext_vector_type(8))) _Float16 f16x8;
typedef __attribute__((ext_vector_type(2))) _Float16 f16x2;
typedef __attribute__((ext_vector_type(4))) float f32x4;

static __device__ __forceinline__ int wave_incl_scan(int v, int lane) {
#pragma unroll
    for (int off = 1; off < 64; off <<= 1) {
        int u = __shfl_up(v, off, 64);
        if (lane >= off) v += u;
    }
    return v;
}

// ---------------------------------------------------------------------------
// CSR build: histogram -> 3-phase parallel scan -> scatter.
// ---------------------------------------------------------------------------

__global__ void hist_kernel(const int* __restrict__ dst, int* __restrict__ deg, int E) {
    int e = blockIdx.x * blockDim.x + threadIdx.x;
    if (e < E) atomicAdd(&deg[dst[e]], 1);
}

__global__ __launch_bounds__(1024) void scan1_kernel(const int* __restrict__ deg,
                                                     int* __restrict__ row_ptr,
                                                     int* __restrict__ bsum, int N) {
    int i = blockIdx.x * 1024 + threadIdx.x;
    int lane = threadIdx.x & 63;
    int w = threadIdx.x >> 6;
    int v = (i < N) ? deg[i] : 0;
    int inc = wave_incl_scan(v, lane);
    __shared__ int wsum[16];
    if (lane == 63) wsum[w] = inc;
    __syncthreads();
    if (w == 0) {
        int s = (lane < 16) ? wsum[lane] : 0;
        int si = wave_incl_scan(s, lane);
        if (lane < 16) wsum[lane] = si - s;
    }
    __syncthreads();
    int exc = inc - v + wsum[w];
    if (i < N) row_ptr[i] = exc;
    if (threadIdx.x == 1023) bsum[blockIdx.x] = exc + v;
}

__global__ __launch_bounds__(1024) void scan2_kernel(const int* __restrict__ bsum,
                                                     int* __restrict__ boff,
                                                     int* __restrict__ row_ptr,
                                                     int nb, int N, int E) {
    int tid = threadIdx.x;
    int lane = tid & 63;
    int w = tid >> 6;
    int v = (tid < nb) ? bsum[tid] : 0;
    int inc = wave_incl_scan(v, lane);
    __shared__ int wsum[16];
    if (lane == 63) wsum[w] = inc;
    __syncthreads();
    if (w == 0) {
        int s = (lane < 16) ? wsum[lane] : 0;
        int si = wave_incl_scan(s, lane);
        if (lane < 16) wsum[lane] = si - s;
    }
    __syncthreads();
    if (tid < nb) boff[tid] = inc - v + wsum[w];
    if (tid == 0) row_ptr[N] = E;
}

__global__ void scan3_kernel(int* __restrict__ row_ptr, const int* __restrict__ boff, int N) {
    int i = blockIdx.x * blockDim.x + threadIdx.x;
    if (i < N) row_ptr[i] += boff[i >> 10];
}

__global__ void scatter_kernel(const int* __restrict__ src, const int* __restrict__ dst,
                               const int* __restrict__ row_ptr, int* __restrict__ fill,
                               int* __restrict__ esrc, int E) {
    int e = blockIdx.x * blockDim.x + threadIdx.x;
    if (e < E) {
        int d = dst[e];
        int pos = row_ptr[d] + atomicAdd(&fill[d], 1);
        esrc[pos] = src[e];
    }
}

// ---------------------------------------------------------------------------
// fp32 -> fp16 converts (weights once, feats once).
// ---------------------------------------------------------------------------

__global__ void wcvt_kernel(const float* __restrict__ tw, const float* __restrict__ pw,
                            _Float16* __restrict__ wt, _Float16* __restrict__ wp, int n) {
    int i = blockIdx.x * blockDim.x + threadIdx.x;
    if (i < n) { wt[i] = (_Float16)tw[i]; wp[i] = (_Float16)pw[i]; }
}

__global__ void xcvt_kernel(const float* __restrict__ x, _Float16* __restrict__ x16, int n4) {
    int i = blockIdx.x * blockDim.x + threadIdx.x;
    if (i < n4) {
        float4 v = ((const float4*)x)[i];
        f16x2 a, b;
        a[0] = (_Float16)v.x; a[1] = (_Float16)v.y;
        b[0] = (_Float16)v.z; b[1] = (_Float16)v.w;
        ((f16x2*)x16)[i * 2] = a;
        ((f16x2*)x16)[i * 2 + 1] = b;
    }
}

// ---------------------------------------------------------------------------
// Fused MFMA GEMM: t = x @ Wt.T, p = x @ Wp.T in fp16 (fp32 accumulate).
// Block = 4 waves, 128 rows; wave owns 32 cols of BOTH outputs; all B frags
// (theta+phi) live in regs for the whole block; A loaded once per 16-row step
// feeds 32 MFMAs. No LDS, no barriers.
// C/D layout: col = lane&15, row = (lane>>4)*4 + reg.
// ---------------------------------------------------------------------------

__global__ __launch_bounds__(256) void mfma_gemm_kernel(
        const _Float16* __restrict__ x16,
        const _Float16* __restrict__ wt, const _Float16* __restrict__ wp,
        _Float16* __restrict__ t16, _Float16* __restrict__ p16, int M) {
    int lane = threadIdx.x & 63;
    int l16 = lane & 15;
    int quad = lane >> 4;
    int cn0 = (threadIdx.x >> 6) * 32;

    f16x8 bt[2][4], bp[2][4];
#pragma unroll
    for (int ct = 0; ct < 2; ++ct) {
        int col = cn0 + ct * 16 + l16;
#pragma unroll
        for (int kk = 0; kk < 4; ++kk) {
            int k = kk * 32 + quad * 8;
            bt[ct][kk] = *(const f16x8*)(wt + (size_t)col * FEAT + k);
            bp[ct][kk] = *(const f16x8*)(wp + (size_t)col * FEAT + k);
        }
    }

    int rbase0 = blockIdx.x * 128;
#pragma unroll 1
    for (int rs = 0; rs < 8; ++rs) {
        int rbase = rbase0 + rs * 16;
        int row = rbase + l16;
        int rowc = (row < M) ? row : (M - 1);
        f16x8 a[4];
#pragma unroll
        for (int kk = 0; kk < 4; ++kk)
            a[kk] = *(const f16x8*)(x16 + (size_t)rowc * FEAT + kk * 32 + quad * 8);

        f32x4 accT[2] = {{0.f, 0.f, 0.f, 0.f}, {0.f, 0.f, 0.f, 0.f}};
        f32x4 accP[2] = {{0.f, 0.f, 0.f, 0.f}, {0.f, 0.f, 0.f, 0.f}};
#pragma unroll
        for (int kk = 0; kk < 4; ++kk) {
#pragma unroll
            for (int ct = 0; ct < 2; ++ct) {
                accT[ct] = __builtin_amdgcn_mfma_f32_16x16x32_f16(a[kk], bt[ct][kk], accT[ct], 0, 0, 0);
                accP[ct] = __builtin_amdgcn_mfma_f32_16x16x32_f16(a[kk], bp[ct][kk], accP[ct], 0, 0, 0);
            }
        }
#pragma unroll
        for (int ct = 0; ct < 2; ++ct) {
            int col = cn0 + ct * 16 + l16;
#pragma unroll
            for (int r = 0; r < 4; ++r) {
                int ro = rbase + quad * 4 + r;
                if (ro < M) {
                    t16[(size_t)ro * FEAT + col] = (_Float16)accT[ct][r];
                    p16[(size_t)ro * FEAT + col] = (_Float16)accP[ct][r];
                }
            }
        }
    }
}

// ---------------------------------------------------------------------------
// Aggregation + epilogue. One wave per node, lane = feature pair (4 B/lane,
// 256 B/row). Edge indices loaded 64-at-a-time with ONE coalesced load, then
// broadcast via shfl (register-only) -> 4 independent gathers in flight.
// o = relu( max_e t[src_e] - t[i] + tb + pb + p[i] ), 0 for edgeless nodes.
// ---------------------------------------------------------------------------

__global__ __launch_bounds__(256) void agg_kernel(
        const _Float16* __restrict__ t16, const _Float16* __restrict__ p16,
        const float* __restrict__ tb, const float* __restrict__ pb,
        const int* __restrict__ row_ptr, const int* __restrict__ esrc,
        float* __restrict__ outf, _Float16* __restrict__ ox, int N) {
    int wv = threadIdx.x >> 6;
    int lane = threadIdx.x & 63;
    int node = blockIdx.x * 4 + wv;
    if (node >= N) return;

    int beg = row_ptr[node];
    int end = row_ptr[node + 1];

    const f16x2* t2 = (const f16x2*)t16;
    float mx = -__builtin_inff(), my = -__builtin_inff();

    for (int base = beg; base < end; base += 64) {
        int n = end - base;
        if (n > 64) n = 64;
        int myidx = (lane < n) ? esrc[base + lane] : 0;
        int j = 0;
        for (; j + 4 <= n; j += 4) {
            int s0 = __shfl(myidx, j);
            int s1 = __shfl(myidx, j + 1);
            int s2 = __shfl(myidx, j + 2);
            int s3 = __shfl(myidx, j + 3);
            f16x2 v0 = t2[(size_t)s0 * 64 + lane];
            f16x2 v1 = t2[(size_t)s1 * 64 + lane];
            f16x2 v2 = t2[(size_t)s2 * 64 + lane];
            f16x2 v3 = t2[(size_t)s3 * 64 + lane];
            mx = fmaxf(mx, fmaxf(fmaxf((float)v0[0], (float)v1[0]),
                                 fmaxf((float)v2[0], (float)v3[0])));
            my = fmaxf(my, fmaxf(fmaxf((float)v0[1], (float)v1[1]),
                                 fmaxf((float)v2[1], (float)v3[1])));
        }
        for (; j < n; ++j) {
            int s = __shfl(myidx, j);
            f16x2 v = t2[(size_t)s * 64 + lane];
            mx = fmaxf(mx, (float)v[0]);
            my = fmaxf(my, (float)v[1]);
        }
    }

    f16x2 ti = t2[(size_t)node * 64 + lane];
    f16x2 pi = ((const f16x2*)p16)[(size_t)node * 64 + lane];
    float2 tbv = ((const float2*)tb)[lane];
    float2 pbv = ((const float2*)pb)[lane];

    float ox_ = 0.f, oy_ = 0.f;
    if (beg < end) {
        ox_ = fmaxf(mx - (float)ti[0] + tbv.x + pbv.x + (float)pi[0], 0.f);
        oy_ = fmaxf(my - (float)ti[1] + tbv.y + pbv.y + (float)pi[1], 0.f);
    }

    if (outf) {
        ((float2*)outf)[(size_t)node * 64 + lane] = make_float2(ox_, oy_);
    }
    if (ox) {
        f16x2 o;
        o[0] = (_Float16)ox_;
        o[1] = (_Float16)oy_;
        ((f16x2*)ox)[(size_t)node * 64 + lane] = o;
    }
}

// ---------------------------------------------------------------------------

extern "C" void kernel_launch(void* const* d_in, const int* in_sizes, int n_in,
                              void* d_out, int out_size, void* d_ws, size_t ws_size,
                              hipStream_t stream) {
    const float* feats   = (const float*)d_in[0];
    const int*   src     = (const int*)d_in[1];
    const int*   dst     = (const int*)d_in[2];
    const float* theta_w = (const float*)d_in[3];
    const float* theta_b = (const float*)d_in[4];
    const float* phi_w   = (const float*)d_in[5];
    const float* phi_b   = (const float*)d_in[6];

    const int N = in_sizes[0] / FEAT;
    const int E = in_sizes[1];
    const int L = in_sizes[3] / (FEAT * FEAT);

    char* ws = (char*)d_ws;
    size_t off = 0;
    auto alloc = [&](size_t bytes) -> void* {
        void* ptr = ws + off;
        off = (off + bytes + 255) & ~(size_t)255;
        return ptr;
    };
    _Float16* t16 = (_Float16*)alloc((size_t)N * FEAT * 2);
    _Float16* p16 = (_Float16*)alloc((size_t)N * FEAT * 2);
    _Float16* x16 = (_Float16*)alloc((size_t)N * FEAT * 2);
    _Float16* wt16 = (_Float16*)alloc((size_t)L * FEAT * FEAT * 2);
    _Float16* wp16 = (_Float16*)alloc((size_t)L * FEAT * FEAT * 2);
    int* deg     = (int*)alloc((size_t)N * sizeof(int));
    int* fill    = (int*)alloc((size_t)N * sizeof(int));
    int* row_ptr = (int*)alloc((size_t)(N + 1) * sizeof(int));
    int* esrc    = (int*)alloc((size_t)E * sizeof(int));
    int* bsum    = (int*)alloc(2048 * sizeof(int));
    int* boff    = (int*)alloc(2048 * sizeof(int));
    (void)ws_size;

    hipMemsetAsync(deg, 0, (size_t)N * sizeof(int), stream);
    hipMemsetAsync(fill, 0, (size_t)N * sizeof(int), stream);

    int eb = (E + 255) / 256;
    int nb = (N + 1023) >> 10;
    hist_kernel<<<eb, 256, 0, stream>>>(dst, deg, E);
    scan1_kernel<<<nb, 1024, 0, stream>>>(deg, row_ptr, bsum, N);
    scan2_kernel<<<1, 1024, 0, stream>>>(bsum, boff, row_ptr, nb, N, E);
    scan3_kernel<<<(N + 255) / 256, 256, 0, stream>>>(row_ptr, boff, N);
    scatter_kernel<<<eb, 256, 0, stream>>>(src, dst, row_ptr, fill, esrc, E);

    int wn = L * FEAT * FEAT;
    wcvt_kernel<<<(wn + 255) / 256, 256, 0, stream>>>(theta_w, phi_w, wt16, wp16, wn);
    int xn4 = N * FEAT / 4;
    xcvt_kernel<<<(xn4 + 255) / 256, 256, 0, stream>>>(feats, x16, xn4);

    int gb = (N + 127) / 128;
    for (int l = 0; l < L; ++l) {
        mfma_gemm_kernel<<<gb, 256, 0, stream>>>(
            x16,
            wt16 + (size_t)l * FEAT * FEAT,
            wp16 + (size_t)l * FEAT * FEAT,
            t16, p16, N);

        bool last = (l == L - 1);
        agg_kernel<<<(N + 3) / 4, 256, 0, stream>>>(
            t16, p16,
            theta_b + (size_t)l * FEAT,
            phi_b + (size_t)l * FEAT,
            row_ptr, esrc,
            last ? (float*)d_out : nullptr,
            last ? nullptr : x16,   // in-place: x16 fully consumed before agg runs
            N);
    }
}